// Round 12
// baseline (1000.392 us; speedup 1.0000x reference)
//
#include <hip/hip_runtime.h>
#include <hip/hip_bf16.h>

typedef __attribute__((ext_vector_type(8))) short  bf16x8;
typedef __attribute__((ext_vector_type(4))) float  f32x4;
typedef __attribute__((ext_vector_type(4))) int    i32x4;
typedef __attribute__((address_space(3))) void       as3void;
typedef const __attribute__((address_space(1))) void as1void;

#define B_   8
#define R_   4
#define N_   2048
#define S_   6
#define DIN  32
#define DOUT 32
#define NT   16    // K-supertiles of BK=128

// ---------------------------------------------------------------------------
// Pre-kernel: XW_T[b][r][e][m] = bf16( coef[r] * sum_d X[b,r,m,d] * fc_w[r,d,e] )
// ---------------------------------------------------------------------------
__global__ __launch_bounds__(256) void prep_xw(
    const float* __restrict__ theta, const float* __restrict__ tpar,
    const float* __restrict__ X,     const float* __restrict__ fcw,
    __hip_bfloat16* __restrict__ xwt)
{
    int br    = blockIdx.x >> 5;
    int mtile = blockIdx.x & 31;
    int r     = br & 3;
    int t     = threadIdx.x;
    int m     = mtile * 64 + (t & 63);
    int egrp  = t >> 6;

    float coef = 0.f;
#pragma unroll
    for (int s = 0; s < S_; ++s) coef += theta[r * S_ + s] * tpar[r * S_ + s];

    const float* xrow = X + ((size_t)br * N_ + m) * DIN;
    float xr[DIN];
#pragma unroll
    for (int i = 0; i < DIN / 4; ++i) {
        f32x4 v = *(const f32x4*)(xrow + i * 4);
        xr[i * 4 + 0] = v.x; xr[i * 4 + 1] = v.y;
        xr[i * 4 + 2] = v.z; xr[i * 4 + 3] = v.w;
    }
#pragma unroll
    for (int eb = 0; eb < 8; ++eb) {
        int e = egrp * 8 + eb;
        float acc = 0.f;
#pragma unroll
        for (int d = 0; d < DIN; ++d) acc += xr[d] * fcw[(r * DIN + d) * DOUT + e];
        xwt[((size_t)br * DOUT + e) * N_ + m] = __float2bfloat16(coef * acc);
    }
}

// ---------------------------------------------------------------------------
// PROBE P1: pure HBM READ, linear grid-stride, NONTEMPORAL loads (no L3
// retention -> FETCH_SIZE must show ~2.7GB; rate = 2.7GB/dur is the chip's
// true pure-read ceiling). 5 passes x 537MB so dur > fills' ~330us (top-5).
// anti-CSE: empty asm "modifies" off each pass so addresses can't fold.
// ---------------------------------------------------------------------------
__global__ __launch_bounds__(256) void nt_probe_linear(
    const float* __restrict__ A, float* __restrict__ sink)
{
    size_t tid = (size_t)blockIdx.x * 256 + threadIdx.x;   // 262144 threads
    const char* base = (const char*)A;
    int off = 0;
    f32x4 acc = {0.f, 0.f, 0.f, 0.f};
#pragma clang loop unroll(disable)
    for (int pass = 0; pass < 5; ++pass) {
        asm volatile("" : "+v"(off));
        const f32x4* p = (const f32x4*)(base + (size_t)off) + tid;
#pragma unroll 8
        for (int i = 0; i < 128; ++i) {
            f32x4 v = __builtin_nontemporal_load(p + (size_t)i * 262144);
            acc.x += v.x; acc.y += v.y; acc.z += v.z; acc.w += v.w;
        }
    }
    sink[tid] = acc.x + acc.y + acc.z + acc.w;
}

// ---------------------------------------------------------------------------
// PROBE P2: pure HBM READ in fused_main's EXACT A pattern (1024 blocks, 4
// matrices/block, 16 rows x 512B chunks, 8KB stride), NONTEMPORAL, 5 passes.
// P2 vs P1 separates "pattern caps HBM reads" from "reads are just slow".
// ---------------------------------------------------------------------------
__global__ __launch_bounds__(256) void nt_probe_pattern(
    const float* __restrict__ A, float* __restrict__ sink)
{
    int bid = blockIdx.x;
    int b = bid >> 7, tile = bid & 127;
    int n0 = tile * 16;
    int t = threadIdx.x;
    int r = t >> 6;
    int l = t & 63;
    int hl = l >> 5, l31 = l & 31;
    const char* Ab = (const char*)(A + (((size_t)(b * R_ + r)) * N_ + n0) * N_);
    int off = 0;
    f32x4 acc = {0.f, 0.f, 0.f, 0.f};
#pragma clang loop unroll(disable)
    for (int pass = 0; pass < 5; ++pass) {
        asm volatile("" : "+v"(off));
#pragma clang loop unroll(disable)
        for (int kt = 0; kt < 16; ++kt) {
#pragma unroll
            for (int i = 0; i < 8; ++i) {
                int row = 2 * i + hl;
                const char* p = Ab + (size_t)row * (N_ * 4) + l31 * 16
                              + (size_t)kt * 512 + (size_t)off;
                f32x4 v = __builtin_nontemporal_load((const f32x4*)p);
                acc.x += v.x; acc.y += v.y; acc.z += v.z; acc.w += v.w;
            }
        }
    }
    sink[(size_t)bid * 256 + t] = acc.x + acc.y + acc.z + acc.w;
}

// ---------------------------------------------------------------------------
// Main fused kernel — EXACT R7 (best: 137.98us). Unchanged this round.
// ---------------------------------------------------------------------------
__global__ __launch_bounds__(256) void fused_main(
    const float* __restrict__ A,   const __hip_bfloat16* __restrict__ xwt,
    const float* __restrict__ fcb, const float* __restrict__ cw,
    const float* __restrict__ cb,  const float* __restrict__ p0p,
    const float* __restrict__ p1p, float* __restrict__ out)
{
    __shared__ char smem[65536];

    int bid  = blockIdx.x;
    int b    = bid >> 7;
    int tile = bid & 127;
    int n0   = tile * 16;
    int t    = threadIdx.x;
    int r    = t >> 6;
    int l    = t & 63;
    int row16 = l & 15;
    int kg    = l >> 4;
    int swzr  = (row16 & 7) << 4;
    int ldsbase = r * 8192;
    int hl   = l >> 5;
    int l31  = l & 31;

    const char* Ab = (const char*)(A + (((size_t)(b * R_ + r)) * N_ + n0) * N_);
    const char* srcp[8];
#pragma unroll
    for (int i = 0; i < 8; ++i) {
        int row = 2 * i + hl;
        srcp[i] = Ab + (size_t)row * (N_ * 4) + ((l31 * 16) ^ ((row & 7) << 4));
    }

    const ushort* xw  = (const ushort*)xwt + (size_t)(b * R_ + r) * DOUT * N_;
    const ushort* bp0 = xw + (size_t)row16 * N_        + kg * 8;
    const ushort* bp1 = xw + (size_t)(16 + row16) * N_ + kg * 8;

#define STAGE_A(CUR, KT) do {                                                    \
    _Pragma("unroll")                                                            \
    for (int i_ = 0; i_ < 8; ++i_) {                                             \
        __builtin_amdgcn_global_load_lds(                                        \
            (as1void*)(srcp[i_] + (size_t)(KT) * 512),                           \
            (as3void*)&smem[(CUR) * 32768 + ldsbase + i_ * 1024], 16, 0, 2);     \
    } } while (0)

#define LOADB(P, KT) do {                                                        \
    asm volatile("global_load_dwordx4 %0, %1, off" : "=v"(P##0) : "v"(bp0 + (KT) * 128 +  0)); \
    asm volatile("global_load_dwordx4 %0, %1, off" : "=v"(P##1) : "v"(bp0 + (KT) * 128 + 32)); \
    asm volatile("global_load_dwordx4 %0, %1, off" : "=v"(P##2) : "v"(bp0 + (KT) * 128 + 64)); \
    asm volatile("global_load_dwordx4 %0, %1, off" : "=v"(P##3) : "v"(bp0 + (KT) * 128 + 96)); \
    asm volatile("global_load_dwordx4 %0, %1, off" : "=v"(P##4) : "v"(bp1 + (KT) * 128 +  0)); \
    asm volatile("global_load_dwordx4 %0, %1, off" : "=v"(P##5) : "v"(bp1 + (KT) * 128 + 32)); \
    asm volatile("global_load_dwordx4 %0, %1, off" : "=v"(P##6) : "v"(bp1 + (KT) * 128 + 64)); \
    asm volatile("global_load_dwordx4 %0, %1, off" : "=v"(P##7) : "v"(bp1 + (KT) * 128 + 96)); \
    } while (0)

    f32x4 acc0 = {0.f, 0.f, 0.f, 0.f};
    f32x4 acc1 = {0.f, 0.f, 0.f, 0.f};
    i32x4 bc0, bc1, bc2, bc3, bc4, bc5, bc6, bc7;
    i32x4 bn0, bn1, bn2, bn3, bn4, bn5, bn6, bn7;

    STAGE_A(0, 0);
    LOADB(bc, 0);

#pragma unroll 2
    for (int kt = 0; kt < NT; ++kt) {
        int cur = kt & 1;
        __builtin_amdgcn_sched_barrier(0);
        if (kt < NT - 1) {
            STAGE_A(cur ^ 1, kt + 1);
            LOADB(bn, kt + 1);
            __builtin_amdgcn_sched_barrier(0);
            asm volatile("s_waitcnt vmcnt(16)" ::: "memory");
        } else {
            __builtin_amdgcn_sched_barrier(0);
            asm volatile("s_waitcnt vmcnt(0)" ::: "memory");
        }
        __builtin_amdgcn_sched_barrier(0);

        {
            const char* abuf = &smem[cur * 32768 + ldsbase];
            int rbase = row16 * 512;
#define KSTEP(KS, BA, BB) do {                                                   \
    f32x4 lo = *(const f32x4*)(abuf + rbase + (((KS) * 128 + kg * 32 +  0) ^ swzr)); \
    f32x4 hi = *(const f32x4*)(abuf + rbase + (((KS) * 128 + kg * 32 + 16) ^ swzr)); \
    i32x4 av;                                                                    \
    asm("v_cvt_pk_bf16_f32 %0, %1, %2" : "=v"(av.x) : "v"(lo.x), "v"(lo.y));     \
    asm("v_cvt_pk_bf16_f32 %0, %1, %2" : "=v"(av.y) : "v"(lo.z), "v"(lo.w));     \
    asm("v_cvt_pk_bf16_f32 %0, %1, %2" : "=v"(av.z) : "v"(hi.x), "v"(hi.y));     \
    asm("v_cvt_pk_bf16_f32 %0, %1, %2" : "=v"(av.w) : "v"(hi.z), "v"(hi.w));     \
    bf16x8 af = __builtin_bit_cast(bf16x8, av);                                  \
    acc0 = __builtin_amdgcn_mfma_f32_16x16x32_bf16(af, __builtin_bit_cast(bf16x8, BA), acc0, 0, 0, 0); \
    acc1 = __builtin_amdgcn_mfma_f32_16x16x32_bf16(af, __builtin_bit_cast(bf16x8, BB), acc1, 0, 0, 0); \
    } while (0)
            KSTEP(0, bc0, bc4);
            KSTEP(1, bc1, bc5);
            KSTEP(2, bc2, bc6);
            KSTEP(3, bc3, bc7);
#undef KSTEP
        }
        bc0 = bn0; bc1 = bn1; bc2 = bn2; bc3 = bn3;
        bc4 = bn4; bc5 = bn5; bc6 = bn6; bc7 = bn7;
    }
#undef STAGE_A
#undef LOADB

    float p0 = p0p[0], p1 = p1p[0];

    __syncthreads();
    float (*hlds)[16][DOUT + 1] = (float (*)[16][DOUT + 1])(void*)smem;
#pragma unroll
    for (int j = 0; j < 4; ++j) {
        int rw = kg * 4 + j;
        float v0 = acc0[j] + fcb[r * DOUT + row16];
        float v1 = acc1[j] + fcb[r * DOUT + 16 + row16];
        hlds[r][rw][row16]      = v0 >= 0.f ? v0 : p0 * v0;
        hlds[r][rw][16 + row16] = v1 >= 0.f ? v1 : p0 * v1;
    }
    __syncthreads();

    int q = r;
    float c0 = cw[q * R_ + 0], c1 = cw[q * R_ + 1];
    float c2 = cw[q * R_ + 2], c3 = cw[q * R_ + 3];
    float cbq = cb[q];
    int e  = l & 31;
    int rg = l >> 5;
#pragma unroll
    for (int i = 0; i < 8; ++i) {
        int row = rg * 8 + i;
        float mx = cbq + c0 * hlds[0][row][e] + c1 * hlds[1][row][e]
                       + c2 * hlds[2][row][e] + c3 * hlds[3][row][e];
        float lat = mx >= 0.f ? mx : p1 * mx;
        out[(((size_t)b * R_ + q) * N_ + (n0 + row)) * DOUT + e] = lat;
    }
}

extern "C" void kernel_launch(void* const* d_in, const int* in_sizes, int n_in,
                              void* d_out, int out_size, void* d_ws, size_t ws_size,
                              hipStream_t stream)
{
    const float* theta = (const float*)d_in[0];
    const float* tpar  = (const float*)d_in[1];
    const float* A     = (const float*)d_in[2];
    const float* X     = (const float*)d_in[3];
    const float* fcw   = (const float*)d_in[4];
    const float* fcb   = (const float*)d_in[5];
    const float* cw    = (const float*)d_in[6];
    const float* cb    = (const float*)d_in[7];
    const float* p0    = (const float*)d_in[8];
    const float* p1    = (const float*)d_in[9];

    __hip_bfloat16* xwt = (__hip_bfloat16*)d_ws;                       // [0, 4MiB)
    float* sink1 = (float*)((char*)d_ws + (8u  << 20));                // [8MiB, 9MiB)
    float* sink2 = (float*)((char*)d_ws + (12u << 20));                // [12MiB, 13MiB)

    prep_xw<<<B_ * R_ * (N_ / 64), 256, 0, stream>>>(theta, tpar, X, fcw, xwt);
    fused_main<<<B_ * (N_ / 16), 256, 0, stream>>>(A, xwt, fcb, cw, cb, p0, p1,
                                                   (float*)d_out);
    // --- measurement probes (this round only): pure-HBM-read references ---
    nt_probe_linear <<<1024, 256, 0, stream>>>(A, sink1);
    nt_probe_pattern<<<1024, 256, 0, stream>>>(A, sink2);
}

// Round 13
// 138.257 us; speedup vs baseline: 7.2357x; 7.2357x over previous
//
#include <hip/hip_runtime.h>
#include <hip/hip_bf16.h>

typedef __attribute__((ext_vector_type(8))) short  bf16x8;
typedef __attribute__((ext_vector_type(4))) float  f32x4;
typedef __attribute__((ext_vector_type(4))) int    i32x4;
typedef __attribute__((address_space(3))) void       as3void;
typedef const __attribute__((address_space(1))) void as1void;

#define B_   8
#define R_   4
#define N_   2048
#define S_   6
#define DIN  32
#define DOUT 32
#define NT   16    // K-supertiles of BK=128

// ---------------------------------------------------------------------------
// Pre-kernel: XW_T[b][r][e][m] = bf16( coef[r] * sum_d X[b,r,m,d] * fc_w[r,d,e] )
// coef[r] = sum_s theta[r,s]*t[r,s]. Stored transposed so the main kernel's
// MFMA B-fragment is one contiguous 16B load per lane.
// ---------------------------------------------------------------------------
__global__ __launch_bounds__(256) void prep_xw(
    const float* __restrict__ theta, const float* __restrict__ tpar,
    const float* __restrict__ X,     const float* __restrict__ fcw,
    __hip_bfloat16* __restrict__ xwt)
{
    int br    = blockIdx.x >> 5;
    int mtile = blockIdx.x & 31;
    int r     = br & 3;
    int t     = threadIdx.x;
    int m     = mtile * 64 + (t & 63);
    int egrp  = t >> 6;

    float coef = 0.f;
#pragma unroll
    for (int s = 0; s < S_; ++s) coef += theta[r * S_ + s] * tpar[r * S_ + s];

    const float* xrow = X + ((size_t)br * N_ + m) * DIN;
    float xr[DIN];
#pragma unroll
    for (int i = 0; i < DIN / 4; ++i) {
        f32x4 v = *(const f32x4*)(xrow + i * 4);
        xr[i * 4 + 0] = v.x; xr[i * 4 + 1] = v.y;
        xr[i * 4 + 2] = v.z; xr[i * 4 + 3] = v.w;
    }
#pragma unroll
    for (int eb = 0; eb < 8; ++eb) {
        int e = egrp * 8 + eb;
        float acc = 0.f;
#pragma unroll
        for (int d = 0; d < DIN; ++d) acc += xr[d] * fcw[(r * DIN + d) * DOUT + e];
        xwt[((size_t)br * DOUT + e) * N_ + m] = __float2bfloat16(coef * acc);
    }
}

// ---------------------------------------------------------------------------
// Main fused kernel — FINAL (R7, best measured: 137.98us).
// 4 waves/block (wave r = relation r), 16-row n-tile, BK=128 supertiles.
// A (537MB fp32, read once - the irreducible traffic) staged per-wave into
// private LDS via global_load_lds DMA (NT cache policy), double-buffered,
// counted vmcnt(16), no barriers in the K-loop. Source-side XOR swizzle
// ((row&7)<<4) with linear LDS dest (G21); same XOR on ds_read ->
// conflict-free b128 fragment reads. B (bf16 xwt, L2-resident) in VGPRs via
// volatile asm loads (exact vmcnt accounting). Epilogue fuses fc-bias,
// prelu0, the 4x4 relation conv mix (via LDS, +1 pad), conv-bias, prelu1.
//
// Ceiling evidence (R9/R12 probes): chip read path delivers max 5.5-5.8 TB/s
// to CUs (pure-load ideal kernels); this kernel sustains ~75% of that while
// co-servicing 512MB of L2-side B reads + MFMA. Seven delivery-side
// mechanisms tested null; both DMA and VGPR datapaths plateau here.
// ---------------------------------------------------------------------------
__global__ __launch_bounds__(256) void fused_main(
    const float* __restrict__ A,   const __hip_bfloat16* __restrict__ xwt,
    const float* __restrict__ fcb, const float* __restrict__ cw,
    const float* __restrict__ cb,  const float* __restrict__ p0p,
    const float* __restrict__ p1p, float* __restrict__ out)
{
    __shared__ char smem[65536];   // [buf(2)][wave(4)][16 rows][128 k f32]

    int bid  = blockIdx.x;
    int b    = bid >> 7;
    int tile = bid & 127;
    int n0   = tile * 16;
    int t    = threadIdx.x;
    int r    = t >> 6;
    int l    = t & 63;
    int row16 = l & 15;
    int kg    = l >> 4;
    int swzr  = (row16 & 7) << 4;
    int ldsbase = r * 8192;
    int hl   = l >> 5;
    int l31  = l & 31;

    const char* Ab = (const char*)(A + (((size_t)(b * R_ + r)) * N_ + n0) * N_);
    const char* srcp[8];
#pragma unroll
    for (int i = 0; i < 8; ++i) {
        int row = 2 * i + hl;
        srcp[i] = Ab + (size_t)row * (N_ * 4) + ((l31 * 16) ^ ((row & 7) << 4));
    }

    const ushort* xw  = (const ushort*)xwt + (size_t)(b * R_ + r) * DOUT * N_;
    const ushort* bp0 = xw + (size_t)row16 * N_        + kg * 8;
    const ushort* bp1 = xw + (size_t)(16 + row16) * N_ + kg * 8;

#define STAGE_A(CUR, KT) do {                                                    \
    _Pragma("unroll")                                                            \
    for (int i_ = 0; i_ < 8; ++i_) {                                             \
        __builtin_amdgcn_global_load_lds(                                        \
            (as1void*)(srcp[i_] + (size_t)(KT) * 512),                           \
            (as3void*)&smem[(CUR) * 32768 + ldsbase + i_ * 1024], 16, 0, 2);     \
    } } while (0)

#define LOADB(P, KT) do {                                                        \
    asm volatile("global_load_dwordx4 %0, %1, off" : "=v"(P##0) : "v"(bp0 + (KT) * 128 +  0)); \
    asm volatile("global_load_dwordx4 %0, %1, off" : "=v"(P##1) : "v"(bp0 + (KT) * 128 + 32)); \
    asm volatile("global_load_dwordx4 %0, %1, off" : "=v"(P##2) : "v"(bp0 + (KT) * 128 + 64)); \
    asm volatile("global_load_dwordx4 %0, %1, off" : "=v"(P##3) : "v"(bp0 + (KT) * 128 + 96)); \
    asm volatile("global_load_dwordx4 %0, %1, off" : "=v"(P##4) : "v"(bp1 + (KT) * 128 +  0)); \
    asm volatile("global_load_dwordx4 %0, %1, off" : "=v"(P##5) : "v"(bp1 + (KT) * 128 + 32)); \
    asm volatile("global_load_dwordx4 %0, %1, off" : "=v"(P##6) : "v"(bp1 + (KT) * 128 + 64)); \
    asm volatile("global_load_dwordx4 %0, %1, off" : "=v"(P##7) : "v"(bp1 + (KT) * 128 + 96)); \
    } while (0)

    f32x4 acc0 = {0.f, 0.f, 0.f, 0.f};
    f32x4 acc1 = {0.f, 0.f, 0.f, 0.f};
    i32x4 bc0, bc1, bc2, bc3, bc4, bc5, bc6, bc7;
    i32x4 bn0, bn1, bn2, bn3, bn4, bn5, bn6, bn7;

    STAGE_A(0, 0);
    LOADB(bc, 0);

#pragma unroll 2
    for (int kt = 0; kt < NT; ++kt) {
        int cur = kt & 1;
        __builtin_amdgcn_sched_barrier(0);
        if (kt < NT - 1) {
            STAGE_A(cur ^ 1, kt + 1);
            LOADB(bn, kt + 1);
            __builtin_amdgcn_sched_barrier(0);
            asm volatile("s_waitcnt vmcnt(16)" ::: "memory");  // cur's 16 done
        } else {
            __builtin_amdgcn_sched_barrier(0);
            asm volatile("s_waitcnt vmcnt(0)" ::: "memory");
        }
        __builtin_amdgcn_sched_barrier(0);

        {   // COMPUTE on buf[cur]: 4 MFMA k-steps of 32
            const char* abuf = &smem[cur * 32768 + ldsbase];
            int rbase = row16 * 512;
#define KSTEP(KS, BA, BB) do {                                                   \
    f32x4 lo = *(const f32x4*)(abuf + rbase + (((KS) * 128 + kg * 32 +  0) ^ swzr)); \
    f32x4 hi = *(const f32x4*)(abuf + rbase + (((KS) * 128 + kg * 32 + 16) ^ swzr)); \
    i32x4 av;                                                                    \
    asm("v_cvt_pk_bf16_f32 %0, %1, %2" : "=v"(av.x) : "v"(lo.x), "v"(lo.y));     \
    asm("v_cvt_pk_bf16_f32 %0, %1, %2" : "=v"(av.y) : "v"(lo.z), "v"(lo.w));     \
    asm("v_cvt_pk_bf16_f32 %0, %1, %2" : "=v"(av.z) : "v"(hi.x), "v"(hi.y));     \
    asm("v_cvt_pk_bf16_f32 %0, %1, %2" : "=v"(av.w) : "v"(hi.z), "v"(hi.w));     \
    bf16x8 af = __builtin_bit_cast(bf16x8, av);                                  \
    acc0 = __builtin_amdgcn_mfma_f32_16x16x32_bf16(af, __builtin_bit_cast(bf16x8, BA), acc0, 0, 0, 0); \
    acc1 = __builtin_amdgcn_mfma_f32_16x16x32_bf16(af, __builtin_bit_cast(bf16x8, BB), acc1, 0, 0, 0); \
    } while (0)
            KSTEP(0, bc0, bc4);
            KSTEP(1, bc1, bc5);
            KSTEP(2, bc2, bc6);
            KSTEP(3, bc3, bc7);
#undef KSTEP
        }
        bc0 = bn0; bc1 = bn1; bc2 = bn2; bc3 = bn3;
        bc4 = bn4; bc5 = bn5; bc6 = bn6; bc7 = bn7;
    }
#undef STAGE_A
#undef LOADB

    float p0 = p0p[0], p1 = p1p[0];

    __syncthreads();   // all waves done with A buffers before hlds overlays smem
    float (*hlds)[16][DOUT + 1] = (float (*)[16][DOUT + 1])(void*)smem;
#pragma unroll
    for (int j = 0; j < 4; ++j) {
        int rw = kg * 4 + j;
        float v0 = acc0[j] + fcb[r * DOUT + row16];
        float v1 = acc1[j] + fcb[r * DOUT + 16 + row16];
        hlds[r][rw][row16]      = v0 >= 0.f ? v0 : p0 * v0;
        hlds[r][rw][16 + row16] = v1 >= 0.f ? v1 : p0 * v1;
    }
    __syncthreads();

    int q = r;
    float c0 = cw[q * R_ + 0], c1 = cw[q * R_ + 1];
    float c2 = cw[q * R_ + 2], c3 = cw[q * R_ + 3];
    float cbq = cb[q];
    int e  = l & 31;
    int rg = l >> 5;
#pragma unroll
    for (int i = 0; i < 8; ++i) {
        int row = rg * 8 + i;
        float mx = cbq + c0 * hlds[0][row][e] + c1 * hlds[1][row][e]
                       + c2 * hlds[2][row][e] + c3 * hlds[3][row][e];
        float lat = mx >= 0.f ? mx : p1 * mx;
        out[(((size_t)b * R_ + q) * N_ + (n0 + row)) * DOUT + e] = lat;
    }
}

extern "C" void kernel_launch(void* const* d_in, const int* in_sizes, int n_in,
                              void* d_out, int out_size, void* d_ws, size_t ws_size,
                              hipStream_t stream)
{
    const float* theta = (const float*)d_in[0];
    const float* tpar  = (const float*)d_in[1];
    const float* A     = (const float*)d_in[2];
    const float* X     = (const float*)d_in[3];
    const float* fcw   = (const float*)d_in[4];
    const float* fcb   = (const float*)d_in[5];
    const float* cw    = (const float*)d_in[6];
    const float* cb    = (const float*)d_in[7];
    const float* p0    = (const float*)d_in[8];
    const float* p1    = (const float*)d_in[9];

    __hip_bfloat16* xwt = (__hip_bfloat16*)d_ws;   // 4 MiB

    prep_xw<<<B_ * R_ * (N_ / 64), 256, 0, stream>>>(theta, tpar, X, fcw, xwt);
    fused_main<<<B_ * (N_ / 16), 256, 0, stream>>>(A, xwt, fcb, cw, cb, p0, p1,
                                                   (float*)d_out);
}